// Round 2
// baseline (488.479 us; speedup 1.0000x reference)
//
#include <hip/hip_runtime.h>

// Biaffine, right-to-left association, MFMA bf16, pre-cast W:
//   Wb16[o,i,j] = bwn0 * W_bil[o,i,j]            (bf16, j<512, prep once)
//   u512[by,o]  = bwn0*(x2b . W_bil[o,512,:]) + bwn1*(x2 . W_lin[512:,o] + b_lin[o])
//   U'[y,o,i]   = (x2b16 @ Wb16[o]^T) + bwn0*W_bil[o,i,512] + bwn1*W_lin[i,o]  (bf16)
//   out[b,x,y,o]= sum_i x1b16[x,i]*U'[y,o,i] + u512[by,o]
// R2: passA/passB K-loop -> 4-deep LDS ring, counted vmcnt (8/4/0) + raw s_barrier
//     (T3/T4); T2 chunk-XOR swizzle (pre-swizzled global src, swizzled frag read);
//     T5 setprio around MFMA; XCD-chunked o-grouping in passA.
// ws: x1b16 1MB | x2b16 1MB | u512 .5MB | W512T .25MB | Wb16 64MiB | Up 134MB ~= 195MiB

#define LL 256
#define DD 512
#define OO 128
#define BB 4
#define WB_OI 263169   // 513*513
#define WB_R512 262656 // 512*513

typedef __attribute__((ext_vector_type(8))) short  short8;
typedef __attribute__((ext_vector_type(8))) unsigned short us8;
typedef __attribute__((ext_vector_type(4))) unsigned short us4;
typedef __attribute__((ext_vector_type(4))) float  f32x4;

__device__ __forceinline__ unsigned short f2bf(float f) {
    unsigned int u = __builtin_bit_cast(unsigned int, f);
    u = (u + 0x7FFFu + ((u >> 16) & 1u)) >> 16;
    return (unsigned short)u;
}
__device__ __forceinline__ float bf2f(unsigned short s) {
    return __builtin_bit_cast(float, (unsigned int)s << 16);
}
__device__ __forceinline__ void load_lds16(const void* g, void* l) {
    __builtin_amdgcn_global_load_lds(
        (const __attribute__((address_space(1))) unsigned int*)g,
        (__attribute__((address_space(3))) unsigned int*)l, 16, 0, 0);
}

// ---- cast fp32 -> bf16 (x1 and x2 in one launch) ----
__global__ __launch_bounds__(256) void cast2_kernel(
    const float* __restrict__ x1, const float* __restrict__ x2,
    unsigned short* __restrict__ x1b, unsigned short* __restrict__ x2b)
{
    int i = blockIdx.x * 256 + threadIdx.x;        // 0 .. 262143 (2 * 131072 float4)
    const float* s; unsigned short* d; int j;
    if (i < 131072) { s = x1; d = x1b; j = i; }
    else            { s = x2; d = x2b; j = i - 131072; }
    float4 v = ((const float4*)s)[j];
    us4 u; u.x = f2bf(v.x); u.y = f2bf(v.y); u.z = f2bf(v.z); u.w = f2bf(v.w);
    *(us4*)(d + (size_t)j * 4) = u;
}

// ---- prep: Wb16[o*512+i][j] = bf16(bwn0 * W_bil[o,i,j]), j<512. 4 rows/block.
//      Lane-interleaved scalar dword loads: always 4B-aligned & fully coalesced. ----
__global__ __launch_bounds__(256) void prepw_kernel(
    const float* __restrict__ Wb, const float* __restrict__ bw,
    unsigned short* __restrict__ Wb16)
{
    const int t = threadIdx.x;
    const int row = blockIdx.x * 4 + (t >> 6);   // o*512 + i
    const int o = row >> 9, i = row & 511;
    const int l = t & 63;
    const float e0 = __expf(bw[0]), e1 = __expf(bw[1]);
    const float bwn0 = e0 / (e0 + e1);
    const float* src = Wb + (size_t)o * WB_OI + (size_t)i * 513;
    unsigned short* dst = Wb16 + (size_t)row * 512;
    float v[8];
    #pragma unroll
    for (int e = 0; e < 8; ++e) v[e] = src[e * 64 + l];
    #pragma unroll
    for (int e = 0; e < 8; ++e) dst[e * 64 + l] = f2bf(bwn0 * v[e]);
}

// ---- prep: W512T[j*128+o] = W_bil[o,512,j], j<513 (tiny, makes u512 coalesced) ----
__global__ __launch_bounds__(256) void prep512_kernel(
    const float* __restrict__ Wb, float* __restrict__ W512T)
{
    int idx = blockIdx.x * 256 + threadIdx.x;    // j*128 + o
    if (idx < 513 * 128) {
        const int o = idx & 127, j = idx >> 7;
        W512T[idx] = Wb[(size_t)o * WB_OI + WB_R512 + j];
    }
}

// ---- u512[by,o], all batches, linear path folded; coalesced via W512T ----
__global__ __launch_bounds__(128) void u512_kernel(
    const float* __restrict__ x2, const float* __restrict__ W512T,
    const float* __restrict__ W_lin, const float* __restrict__ b_lin,
    const float* __restrict__ bw, float* __restrict__ u512buf)
{
    __shared__ float xs[DD];
    const int by = blockIdx.x;   // 0..1023
    const int o  = threadIdx.x;
    const float* xr = x2 + (size_t)by * DD;
    for (int j = o; j < DD; j += 128) xs[j] = xr[j];
    __syncthreads();
    float s1 = W512T[512 * 128 + o];    // j=512 (ones col of x2b)
    float s2 = b_lin[o];
    #pragma unroll 4
    for (int j = 0; j < DD; ++j) {
        s1 += xs[j] * W512T[j * 128 + o];
        s2 += xs[j] * W_lin[(size_t)(DD + j) * OO + o];
    }
    const float e0 = __expf(bw[0]), e1 = __expf(bw[1]);
    const float bwn0 = e0 / (e0 + e1), bwn1 = e1 / (e0 + e1);
    u512buf[(size_t)by * OO + o] = bwn0 * s1 + bwn1 * s2;
}

// ---- pass A: U'[yg,o,i] = (x2b16 @ Wb16[o]^T) + corr[i]; 128x128 tile, K=512 ----
// 1-D grid 4096 (XCD-chunked: each o's 32 blocks on one XCD), block 256 (2x2 waves)
// 4-deep LDS ring, counted vmcnt, T2 chunk swizzle, T5 setprio.
__global__ __launch_bounds__(256) void passA_kernel(
    const unsigned short* __restrict__ x2b, const unsigned short* __restrict__ Wb16,
    const float* __restrict__ W_bil, const float* __restrict__ W_lin,
    const float* __restrict__ bw, unsigned short* __restrict__ Up)
{
    __shared__ __align__(16) char smem[65536];   // 4 stages x (A 8KB + B 8KB)
    unsigned short* Cs  = (unsigned short*)smem;           // [64][136] epilogue reuse
    float* corr = (float*)(smem + 17408);                  // [128]   (stage-1 region)

    const int t = threadIdx.x, w = t >> 6, l = t & 63;
    const int id  = blockIdx.x;                  // 0..4095
    const int lin = (id & 7) * 512 + (id >> 3);  // bijective: XCD c gets lin chunk
    const int o   = lin >> 5;                    // 16 consecutive o per XCD chunk
    const int ib  = (lin & 3) * 128;
    const int yg  = ((lin >> 2) & 7) * 128;
    const int wy = w & 1, wx = w >> 1;

    f32x4 acc[4][4] = {};
    const unsigned short* Wo16 = Wb16 + (size_t)o * DD * DD;

    const int rb0 = w * 32;
    const int rr  = l >> 2;                               // 0..15
    const int kof = ((l & 3) ^ ((l >> 3) & 3)) * 8;       // pre-swizzled src chunk

#define STAGE_A(S, K0) do {                                                     \
    unsigned short* As_ = (unsigned short*)(smem + (S) * 16384);                \
    unsigned short* Bs_ = As_ + 4096;                                           \
    _Pragma("unroll")                                                           \
    for (int q = 0; q < 2; ++q) {                                               \
        const int rb = rb0 + q * 16, rrow = rb + rr, ko = (K0) + kof;           \
        load_lds16(x2b  + (size_t)(yg + rrow) * DD + ko, As_ + rb * 32);        \
        load_lds16(Wo16 + (size_t)(ib + rrow) * DD + ko, Bs_ + rb * 32);        \
    } } while (0)

    STAGE_A(0, 0); STAGE_A(1, 32); STAGE_A(2, 64);

    const int mrow = wy * 64 + (l & 15);
    const int ncol = wx * 64 + (l & 15);
    const int psel = ((l >> 4) ^ ((l >> 1) & 3)) * 8;     // swizzled read slot

#define COMPUTE_T(S) do {                                                       \
    const unsigned short* As_ = (const unsigned short*)(smem + (S) * 16384);    \
    const unsigned short* Bs_ = As_ + 4096;                                     \
    short8 af[4], bfr[4];                                                       \
    _Pragma("unroll")                                                           \
    for (int mt = 0; mt < 4; ++mt) af[mt]  = *(const short8*)(As_ + (mrow + mt * 16) * 32 + psel); \
    _Pragma("unroll")                                                           \
    for (int nt = 0; nt < 4; ++nt) bfr[nt] = *(const short8*)(Bs_ + (ncol + nt * 16) * 32 + psel); \
    __builtin_amdgcn_s_setprio(1);                                              \
    _Pragma("unroll")                                                           \
    for (int mt = 0; mt < 4; ++mt)                                              \
        _Pragma("unroll")                                                       \
        for (int nt = 0; nt < 4; ++nt)                                          \
            acc[mt][nt] = __builtin_amdgcn_mfma_f32_16x16x32_bf16(af[mt], bfr[nt], acc[mt][nt], 0, 0, 0); \
    __builtin_amdgcn_s_setprio(0);                                              \
  } while (0)

    #pragma unroll
    for (int kt = 0; kt < 14; ++kt) {
        asm volatile("s_waitcnt vmcnt(8)" ::: "memory");  // own tile-kt loads done
        __builtin_amdgcn_s_barrier();                     // all waves' tile-kt done
        asm volatile("" ::: "memory");
        if (kt < 13) STAGE_A((kt + 3) & 3, (kt + 3) * 32);
        COMPUTE_T(kt & 3);
    }
    asm volatile("s_waitcnt vmcnt(4)" ::: "memory");
    __builtin_amdgcn_s_barrier();
    asm volatile("" ::: "memory");
    COMPUTE_T(2);
    asm volatile("s_waitcnt vmcnt(0)" ::: "memory");
    __builtin_amdgcn_s_barrier();
    asm volatile("" ::: "memory");
    COMPUTE_T(3);
#undef STAGE_A

    __syncthreads();    // stage buffers now free for epilogue reuse
    const float e0 = __expf(bw[0]), e1 = __expf(bw[1]);
    const float bwn0 = e0 / (e0 + e1), bwn1 = e1 / (e0 + e1);
    if (t < 128) {
        const int ig = ib + t;
        corr[t] = bwn1 * W_lin[(size_t)ig * OO + o]
                + bwn0 * W_bil[(size_t)o * WB_OI + (size_t)ig * 513 + 512];
    }
    // two-half epilogue through 64x136 LDS transpose buffer
    #pragma unroll
    for (int half = 0; half < 2; ++half) {
        if (wy == half) {
            #pragma unroll
            for (int mt = 0; mt < 4; ++mt) {
                const int yl = mt * 16 + ((l >> 4) << 2);   // local row in half
                #pragma unroll
                for (int nt = 0; nt < 4; ++nt) {
                    const int ic = wx * 64 + nt * 16 + (l & 15);
                    #pragma unroll
                    for (int r = 0; r < 4; ++r)
                        Cs[(yl + r) * 136 + ic] = f2bf(acc[mt][nt][r]);
                }
            }
        }
        __syncthreads();
        #pragma unroll
        for (int p = 0; p < 4; ++p) {
            const int yl = p * 16 + (t >> 4);
            const int i0 = (t & 15) * 8;
            short8 v = *(const short8*)(Cs + yl * 136 + i0);
            us8 uo;
            #pragma unroll
            for (int e = 0; e < 8; ++e)
                uo[e] = f2bf(bf2f((unsigned short)v[e]) + corr[i0 + e]);
            *(us8*)(Up + ((size_t)(yg + half * 64 + yl) * OO + o) * DD + ib + i0) = uo;
        }
        __syncthreads();
    }
}

// ---- pass B: out[b,x,y,:] = x1b16 @ U'[yg]^T + u512[yg,:] ----
// grid (2 x-tiles, 1024 yg), block 256; same ring/vmcnt/swizzle structure.
__global__ __launch_bounds__(256) void passB_kernel(
    const unsigned short* __restrict__ x1b, const unsigned short* __restrict__ Up,
    const float* __restrict__ u512buf, float* __restrict__ out)
{
    __shared__ __align__(16) char smem[65536];   // 4 stages x (A 8KB + B 8KB)

    const int t = threadIdx.x, w = t >> 6, l = t & 63;
    const int xb = blockIdx.x * 128;
    const int yg = blockIdx.y;           // 0..1023
    const int bb = yg >> 8, y = yg & 255;
    const int wy = w & 1, wx = w >> 1;

    f32x4 acc[4][4] = {};

    const int rb0 = w * 32;
    const int rr  = l >> 2;
    const int kof = ((l & 3) ^ ((l >> 3) & 3)) * 8;

#define STAGE_B(S, K0) do {                                                          \
    unsigned short* As_ = (unsigned short*)(smem + (S) * 16384);                     \
    unsigned short* Bs_ = As_ + 4096;                                                \
    _Pragma("unroll")                                                                \
    for (int q = 0; q < 2; ++q) {                                                    \
        const int rb = rb0 + q * 16, rrow = rb + rr, ko = (K0) + kof;                \
        load_lds16(x1b + (size_t)(bb * LL + xb + rrow) * DD + ko, As_ + rb * 32);    \
        load_lds16(Up  + (size_t)(yg * OO + rrow) * DD + ko,      Bs_ + rb * 32);    \
    } } while (0)

    STAGE_B(0, 0); STAGE_B(1, 32); STAGE_B(2, 64);

    const int mrow = wy * 64 + (l & 15);
    const int ncol = wx * 64 + (l & 15);
    const int psel = ((l >> 4) ^ ((l >> 1) & 3)) * 8;

    #pragma unroll
    for (int kt = 0; kt < 14; ++kt) {
        asm volatile("s_waitcnt vmcnt(8)" ::: "memory");
        __builtin_amdgcn_s_barrier();
        asm volatile("" ::: "memory");
        if (kt < 13) STAGE_B((kt + 3) & 3, (kt + 3) * 32);
        COMPUTE_T(kt & 3);
    }
    asm volatile("s_waitcnt vmcnt(4)" ::: "memory");
    __builtin_amdgcn_s_barrier();
    asm volatile("" ::: "memory");
    COMPUTE_T(2);
    asm volatile("s_waitcnt vmcnt(0)" ::: "memory");
    __builtin_amdgcn_s_barrier();
    asm volatile("" ::: "memory");
    COMPUTE_T(3);
#undef STAGE_B

    #pragma unroll
    for (int mt = 0; mt < 4; ++mt) {
        const int xr = wy * 64 + mt * 16 + ((l >> 4) << 2);
        #pragma unroll
        for (int nt = 0; nt < 4; ++nt) {
            const int oc = wx * 64 + nt * 16 + (l & 15);
            const float c = u512buf[(size_t)yg * OO + oc];
            #pragma unroll
            for (int r = 0; r < 4; ++r)
                out[((size_t)(bb * LL + xb + xr + r) * LL + y) * OO + oc] = acc[mt][nt][r] + c;
        }
    }
}

extern "C" void kernel_launch(void* const* d_in, const int* in_sizes, int n_in,
                              void* d_out, int out_size, void* d_ws, size_t ws_size,
                              hipStream_t stream)
{
    const float* x1    = (const float*)d_in[0];
    const float* x2    = (const float*)d_in[1];
    const float* bw    = (const float*)d_in[2];
    const float* W_bil = (const float*)d_in[3];
    const float* W_lin = (const float*)d_in[4];
    const float* b_lin = (const float*)d_in[5];
    float* out = (float*)d_out;

    char* ws = (char*)d_ws;
    unsigned short* x1b16 = (unsigned short*)ws;                         // 1 MB
    unsigned short* x2b16 = (unsigned short*)(ws + (1u << 20));          // 1 MB
    float*          u512b = (float*)(ws + (2u << 20));                   // 512 KB
    float*          W512T = (float*)(ws + (2u << 20) + (512u << 10));    // 257 KB
    unsigned short* Wb16  = (unsigned short*)(ws + (3u << 20));          // 64 MiB
    unsigned short* Up    = (unsigned short*)(ws + (3u << 20) + ((size_t)128 * 512 * 512 * 2)); // 134 MB

    cast2_kernel<<<1024, 256, 0, stream>>>(x1, x2, x1b16, x2b16);
    prepw_kernel<<<16384, 256, 0, stream>>>(W_bil, bw, Wb16);
    prep512_kernel<<<257, 256, 0, stream>>>(W_bil, W512T);
    u512_kernel<<<BB * LL, 128, 0, stream>>>(x2, W512T, W_lin, b_lin, bw, u512b);

    passA_kernel<<<4096, 256, 0, stream>>>(x2b16, Wb16, W_bil, W_lin, bw, Up);
    passB_kernel<<<dim3(2, BB * LL), 256, 0, stream>>>(x1b16, Up, u512b, out);
}

// Round 3
// 484.782 us; speedup vs baseline: 1.0076x; 1.0076x over previous
//
#include <hip/hip_runtime.h>

// Biaffine, right-to-left association, MFMA bf16, pre-cast W:
//   Wb16[o,i,j] = bwn0 * W_bil[o,i,j]            (bf16, j<512, prep once)
//   u512[by,o]  = bwn0*(x2b . W_bil[o,512,:]) + bwn1*(x2 . W_lin[512:,o] + b_lin[o])
//   U'[y,o,i]   = (x2b16 @ Wb16[o]^T) + bwn0*W_bil[o,i,512] + bwn1*W_lin[i,o]  (bf16)
//   out[b,x,y,o]= sum_i x1b16[x,i]*U'[y,o,i] + u512[by,o]
// R3: BK=64 dbuf-2 (64KB LDS, 2 blocks/CU) — 32 MFMA per single vmcnt(0)+barrier
//     (half of R2's sync); stage issued at iter top for full-iter latency cover;
//     8-chunk XOR swizzle both sides; keep XCD remap + setprio + R2 epilogues.
// ws: x1b16 1MB | x2b16 1MB | u512 .5MB | W512T .25MB | Wb16 64MiB | Up 134MB ~= 195MiB

#define LL 256
#define DD 512
#define OO 128
#define BB 4
#define WB_OI 263169   // 513*513
#define WB_R512 262656 // 512*513

typedef __attribute__((ext_vector_type(8))) short  short8;
typedef __attribute__((ext_vector_type(8))) unsigned short us8;
typedef __attribute__((ext_vector_type(4))) unsigned short us4;
typedef __attribute__((ext_vector_type(4))) float  f32x4;

__device__ __forceinline__ unsigned short f2bf(float f) {
    unsigned int u = __builtin_bit_cast(unsigned int, f);
    u = (u + 0x7FFFu + ((u >> 16) & 1u)) >> 16;
    return (unsigned short)u;
}
__device__ __forceinline__ float bf2f(unsigned short s) {
    return __builtin_bit_cast(float, (unsigned int)s << 16);
}
__device__ __forceinline__ void load_lds16(const void* g, void* l) {
    __builtin_amdgcn_global_load_lds(
        (const __attribute__((address_space(1))) unsigned int*)g,
        (__attribute__((address_space(3))) unsigned int*)l, 16, 0, 0);
}

// ---- cast fp32 -> bf16 (x1 and x2 in one launch) ----
__global__ __launch_bounds__(256) void cast2_kernel(
    const float* __restrict__ x1, const float* __restrict__ x2,
    unsigned short* __restrict__ x1b, unsigned short* __restrict__ x2b)
{
    int i = blockIdx.x * 256 + threadIdx.x;        // 0 .. 262143 (2 * 131072 float4)
    const float* s; unsigned short* d; int j;
    if (i < 131072) { s = x1; d = x1b; j = i; }
    else            { s = x2; d = x2b; j = i - 131072; }
    float4 v = ((const float4*)s)[j];
    us4 u; u.x = f2bf(v.x); u.y = f2bf(v.y); u.z = f2bf(v.z); u.w = f2bf(v.w);
    *(us4*)(d + (size_t)j * 4) = u;
}

// ---- prep: Wb16[o*512+i][j] = bf16(bwn0 * W_bil[o,i,j]), j<512. 4 rows/block.
//      Lane-interleaved scalar dword loads: always 4B-aligned & fully coalesced. ----
__global__ __launch_bounds__(256) void prepw_kernel(
    const float* __restrict__ Wb, const float* __restrict__ bw,
    unsigned short* __restrict__ Wb16)
{
    const int t = threadIdx.x;
    const int row = blockIdx.x * 4 + (t >> 6);   // o*512 + i
    const int o = row >> 9, i = row & 511;
    const int l = t & 63;
    const float e0 = __expf(bw[0]), e1 = __expf(bw[1]);
    const float bwn0 = e0 / (e0 + e1);
    const float* src = Wb + (size_t)o * WB_OI + (size_t)i * 513;
    unsigned short* dst = Wb16 + (size_t)row * 512;
    float v[8];
    #pragma unroll
    for (int e = 0; e < 8; ++e) v[e] = src[e * 64 + l];
    #pragma unroll
    for (int e = 0; e < 8; ++e) dst[e * 64 + l] = f2bf(bwn0 * v[e]);
}

// ---- prep: W512T[j*128+o] = W_bil[o,512,j], j<513 (tiny, makes u512 coalesced) ----
__global__ __launch_bounds__(256) void prep512_kernel(
    const float* __restrict__ Wb, float* __restrict__ W512T)
{
    int idx = blockIdx.x * 256 + threadIdx.x;    // j*128 + o
    if (idx < 513 * 128) {
        const int o = idx & 127, j = idx >> 7;
        W512T[idx] = Wb[(size_t)o * WB_OI + WB_R512 + j];
    }
}

// ---- u512[by,o], all batches, linear path folded; coalesced via W512T ----
__global__ __launch_bounds__(128) void u512_kernel(
    const float* __restrict__ x2, const float* __restrict__ W512T,
    const float* __restrict__ W_lin, const float* __restrict__ b_lin,
    const float* __restrict__ bw, float* __restrict__ u512buf)
{
    __shared__ float xs[DD];
    const int by = blockIdx.x;   // 0..1023
    const int o  = threadIdx.x;
    const float* xr = x2 + (size_t)by * DD;
    for (int j = o; j < DD; j += 128) xs[j] = xr[j];
    __syncthreads();
    float s1 = W512T[512 * 128 + o];    // j=512 (ones col of x2b)
    float s2 = b_lin[o];
    #pragma unroll 4
    for (int j = 0; j < DD; ++j) {
        s1 += xs[j] * W512T[j * 128 + o];
        s2 += xs[j] * W_lin[(size_t)(DD + j) * OO + o];
    }
    const float e0 = __expf(bw[0]), e1 = __expf(bw[1]);
    const float bwn0 = e0 / (e0 + e1), bwn1 = e1 / (e0 + e1);
    u512buf[(size_t)by * OO + o] = bwn0 * s1 + bwn1 * s2;
}

// Shared compute-phase macro: 8 ds_read_b128 (swizzled) + 16 MFMA for one ks.
// Uses in-scope: smem, mrow, ncol, lk, lx7, acc.
#define PHASE(S, KS) do {                                                       \
    const unsigned short* As_ = (const unsigned short*)(smem + (S) * 32768);    \
    const unsigned short* Bs_ = As_ + 8192;                                     \
    const int ck = (((KS) * 4 + lk) ^ lx7) * 8;                                 \
    short8 af[4], bfr[4];                                                       \
    _Pragma("unroll")                                                           \
    for (int f = 0; f < 4; ++f) af[f]  = *(const short8*)(As_ + (mrow + f * 16) * 64 + ck); \
    _Pragma("unroll")                                                           \
    for (int f = 0; f < 4; ++f) bfr[f] = *(const short8*)(Bs_ + (ncol + f * 16) * 64 + ck); \
    __builtin_amdgcn_s_setprio(1);                                              \
    _Pragma("unroll")                                                           \
    for (int mt = 0; mt < 4; ++mt)                                              \
        _Pragma("unroll")                                                       \
        for (int nt = 0; nt < 4; ++nt)                                          \
            acc[mt][nt] = __builtin_amdgcn_mfma_f32_16x16x32_bf16(af[mt], bfr[nt], acc[mt][nt], 0, 0, 0); \
    __builtin_amdgcn_s_setprio(0);                                              \
  } while (0)

#define WAIT_BAR(N) do {                                                        \
    asm volatile("s_waitcnt vmcnt(" #N ")" ::: "memory");                       \
    __builtin_amdgcn_s_barrier();                                               \
    asm volatile("" ::: "memory");                                              \
  } while (0)

// ---- pass A: U'[yg,o,i] = (x2b16 @ Wb16[o]^T) + corr[i]; 128x128 tile, K=512 ----
// 1-D grid 4096 (XCD-chunked), block 256 (2x2 waves). BK=64 dbuf-2, 1 barrier/K-tile.
__global__ __launch_bounds__(256) void passA_kernel(
    const unsigned short* __restrict__ x2b, const unsigned short* __restrict__ Wb16,
    const float* __restrict__ W_bil, const float* __restrict__ W_lin,
    const float* __restrict__ bw, unsigned short* __restrict__ Up)
{
    __shared__ __align__(16) char smem[65536];   // 2 stages x (A 16KB + B 16KB)
    unsigned short* Cs  = (unsigned short*)smem;           // [64][136] epilogue reuse
    float* corr = (float*)(smem + 17408);                  // [128]

    const int t = threadIdx.x, w = t >> 6, l = t & 63;
    const int id  = blockIdx.x;                  // 0..4095
    const int lin = (id & 7) * 512 + (id >> 3);  // bijective XCD chunking
    const int o   = lin >> 5;                    // 16 consecutive o per XCD chunk
    const int ib  = (lin & 3) * 128;
    const int yg  = ((lin >> 2) & 7) * 128;
    const int wy = w & 1, wx = w >> 1;

    f32x4 acc[4][4] = {};
    const unsigned short* Wo16 = Wb16 + (size_t)o * DD * DD;

    // staging geometry: thread covers 16B chunk (t&7) of rows q*32 + (t>>3);
    // global chunk pre-swizzled by row&7 (matches PHASE read swizzle).
    const int rloc = t >> 3;                     // 0..31
    const int csw  = (t & 7) ^ (rloc & 7);

#define STAGE_A(S, KT) do {                                                     \
    unsigned short* As_ = (unsigned short*)(smem + (S) * 32768);                \
    unsigned short* Bs_ = As_ + 8192;                                           \
    const int gc = (KT) * 64 + csw * 8;                                         \
    _Pragma("unroll")                                                           \
    for (int q = 0; q < 4; ++q) {                                               \
        const int row = q * 32 + rloc;                                          \
        load_lds16(x2b  + (size_t)(yg + row) * DD + gc, As_ + q * 2048 + t * 8);\
        load_lds16(Wo16 + (size_t)(ib + row) * DD + gc, Bs_ + q * 2048 + t * 8);\
    } } while (0)

    const int mrow = wy * 64 + (l & 15);
    const int ncol = wx * 64 + (l & 15);
    const int lk   = l >> 4;                     // 0..3
    const int lx7  = l & 7;

    STAGE_A(0, 0);
    WAIT_BAR(0);
    #pragma unroll
    for (int kt = 0; kt < 8; ++kt) {
        const int cur = kt & 1;
        if (kt < 7) STAGE_A(cur ^ 1, kt + 1);    // issue early: full-iter cover
        PHASE(cur, 0);
        PHASE(cur, 1);
        WAIT_BAR(0);                             // next tile landed; all reads done
    }
#undef STAGE_A

    const float e0 = __expf(bw[0]), e1 = __expf(bw[1]);
    const float bwn0 = e0 / (e0 + e1), bwn1 = e1 / (e0 + e1);
    if (t < 128) {
        const int ig = ib + t;
        corr[t] = bwn1 * W_lin[(size_t)ig * OO + o]
                + bwn0 * W_bil[(size_t)o * WB_OI + (size_t)ig * 513 + 512];
    }
    // two-half epilogue through 64x136 LDS transpose buffer
    #pragma unroll
    for (int half = 0; half < 2; ++half) {
        if (wy == half) {
            #pragma unroll
            for (int mt = 0; mt < 4; ++mt) {
                const int yl = mt * 16 + ((l >> 4) << 2);   // local row in half
                #pragma unroll
                for (int nt = 0; nt < 4; ++nt) {
                    const int ic = wx * 64 + nt * 16 + (l & 15);
                    #pragma unroll
                    for (int r = 0; r < 4; ++r)
                        Cs[(yl + r) * 136 + ic] = f2bf(acc[mt][nt][r]);
                }
            }
        }
        __syncthreads();
        #pragma unroll
        for (int p = 0; p < 4; ++p) {
            const int yl = p * 16 + (t >> 4);
            const int i0 = (t & 15) * 8;
            short8 v = *(const short8*)(Cs + yl * 136 + i0);
            us8 uo;
            #pragma unroll
            for (int e = 0; e < 8; ++e)
                uo[e] = f2bf(bf2f((unsigned short)v[e]) + corr[i0 + e]);
            *(us8*)(Up + ((size_t)(yg + half * 64 + yl) * OO + o) * DD + ib + i0) = uo;
        }
        __syncthreads();
    }
}

// ---- pass B: out[b,x,y,:] = x1b16 @ U'[yg]^T + u512[yg,:] ----
// grid (2 x-tiles, 1024 yg), block 256; same BK=64 dbuf-2 structure.
__global__ __launch_bounds__(256) void passB_kernel(
    const unsigned short* __restrict__ x1b, const unsigned short* __restrict__ Up,
    const float* __restrict__ u512buf, float* __restrict__ out)
{
    __shared__ __align__(16) char smem[65536];   // 2 stages x (A 16KB + B 16KB)

    const int t = threadIdx.x, w = t >> 6, l = t & 63;
    const int xb = blockIdx.x * 128;
    const int yg = blockIdx.y;           // 0..1023
    const int bb = yg >> 8, y = yg & 255;
    const int wy = w & 1, wx = w >> 1;

    f32x4 acc[4][4] = {};

    const int rloc = t >> 3;
    const int csw  = (t & 7) ^ (rloc & 7);

#define STAGE_B(S, KT) do {                                                          \
    unsigned short* As_ = (unsigned short*)(smem + (S) * 32768);                     \
    unsigned short* Bs_ = As_ + 8192;                                                \
    const int gc = (KT) * 64 + csw * 8;                                              \
    _Pragma("unroll")                                                                \
    for (int q = 0; q < 4; ++q) {                                                    \
        const int row = q * 32 + rloc;                                               \
        load_lds16(x1b + (size_t)(bb * LL + xb + row) * DD + gc, As_ + q * 2048 + t * 8); \
        load_lds16(Up  + (size_t)(yg * OO + row) * DD + gc,      Bs_ + q * 2048 + t * 8); \
    } } while (0)

    const int mrow = wy * 64 + (l & 15);
    const int ncol = wx * 64 + (l & 15);
    const int lk   = l >> 4;
    const int lx7  = l & 7;

    STAGE_B(0, 0);
    WAIT_BAR(0);
    #pragma unroll
    for (int kt = 0; kt < 8; ++kt) {
        const int cur = kt & 1;
        if (kt < 7) STAGE_B(cur ^ 1, kt + 1);
        PHASE(cur, 0);
        PHASE(cur, 1);
        WAIT_BAR(0);
    }
#undef STAGE_B

    #pragma unroll
    for (int mt = 0; mt < 4; ++mt) {
        const int xr = wy * 64 + mt * 16 + ((l >> 4) << 2);
        #pragma unroll
        for (int nt = 0; nt < 4; ++nt) {
            const int oc = wx * 64 + nt * 16 + (l & 15);
            const float c = u512buf[(size_t)yg * OO + oc];
            #pragma unroll
            for (int r = 0; r < 4; ++r)
                out[((size_t)(bb * LL + xb + xr + r) * LL + y) * OO + oc] = acc[mt][nt][r] + c;
        }
    }
}

extern "C" void kernel_launch(void* const* d_in, const int* in_sizes, int n_in,
                              void* d_out, int out_size, void* d_ws, size_t ws_size,
                              hipStream_t stream)
{
    const float* x1    = (const float*)d_in[0];
    const float* x2    = (const float*)d_in[1];
    const float* bw    = (const float*)d_in[2];
    const float* W_bil = (const float*)d_in[3];
    const float* W_lin = (const float*)d_in[4];
    const float* b_lin = (const float*)d_in[5];
    float* out = (float*)d_out;

    char* ws = (char*)d_ws;
    unsigned short* x1b16 = (unsigned short*)ws;                         // 1 MB
    unsigned short* x2b16 = (unsigned short*)(ws + (1u << 20));          // 1 MB
    float*          u512b = (float*)(ws + (2u << 20));                   // 512 KB
    float*          W512T = (float*)(ws + (2u << 20) + (512u << 10));    // 257 KB
    unsigned short* Wb16  = (unsigned short*)(ws + (3u << 20));          // 64 MiB
    unsigned short* Up    = (unsigned short*)(ws + (3u << 20) + ((size_t)128 * 512 * 512 * 2)); // 134 MB

    cast2_kernel<<<1024, 256, 0, stream>>>(x1, x2, x1b16, x2b16);
    prepw_kernel<<<16384, 256, 0, stream>>>(W_bil, bw, Wb16);
    prep512_kernel<<<257, 256, 0, stream>>>(W_bil, W512T);
    u512_kernel<<<BB * LL, 128, 0, stream>>>(x2, W512T, W_lin, b_lin, bw, u512b);

    passA_kernel<<<4096, 256, 0, stream>>>(x2b16, Wb16, W_bil, W_lin, bw, Up);
    passB_kernel<<<dim3(2, BB * LL), 256, 0, stream>>>(x1b16, Up, u512b, out);
}